// Round 1
// baseline (1046.925 us; speedup 1.0000x reference)
//
#include <hip/hip_runtime.h>

// GCN: 3x GCNConv(sym-norm, self-loops) + ReLU, mean-pool per graph, FC.
// Strategy: fold dinv into per-layer G = dinv .* (X@W); build dst-CSR once
// per call (histogram + scan + scatter) so aggregation is atomic-free.
// Workspace: ~40 MB (col 12.8MB, G/A 12.8MB each, small arrays).

#define NN 100000
#define EE 3200000
#define FIN 128
#define HID 32
#define NGR 256
#define NC 10

__global__ __launch_bounds__(256) void k_count(const int* __restrict__ dst,
                                               int* __restrict__ deg) {
  int e = blockIdx.x * 256 + threadIdx.x;
  if (e < EE) atomicAdd(&deg[dst[e]], 1);
}

__global__ __launch_bounds__(256) void k_dinv(const int* __restrict__ deg,
                                              float* __restrict__ dinv) {
  int n = blockIdx.x * 256 + threadIdx.x;
  if (n < NN) dinv[n] = rsqrtf((float)(deg[n] + 1));  // +1 = self-loop
}

// Exclusive scan of deg -> row_ptr (3-kernel hierarchical scan).
__global__ __launch_bounds__(256) void k_scanA(const int* __restrict__ in,
                                               int* __restrict__ out,
                                               int* __restrict__ bsums) {
  __shared__ int tmp[256];
  int t = threadIdx.x;
  int base = blockIdx.x * 1024 + t * 4;
  int v[4];
#pragma unroll
  for (int i = 0; i < 4; i++) v[i] = (base + i < NN) ? in[base + i] : 0;
  int s = v[0] + v[1] + v[2] + v[3];
  tmp[t] = s;
  __syncthreads();
#pragma unroll
  for (int off = 1; off < 256; off <<= 1) {
    int x = (t >= off) ? tmp[t - off] : 0;
    __syncthreads();
    tmp[t] += x;
    __syncthreads();
  }
  int excl = tmp[t] - s;
#pragma unroll
  for (int i = 0; i < 4; i++) {
    if (base + i < NN) out[base + i] = excl;
    excl += v[i];
  }
  if (t == 255) bsums[blockIdx.x] = tmp[255];
}

__global__ void k_scanB(int* __restrict__ bsums, int nb) {
  __shared__ int tmp[256];
  int t = threadIdx.x;
  int v = (t < nb) ? bsums[t] : 0;
  tmp[t] = v;
  __syncthreads();
  for (int off = 1; off < 256; off <<= 1) {
    int x = (t >= off) ? tmp[t - off] : 0;
    __syncthreads();
    tmp[t] += x;
    __syncthreads();
  }
  if (t < nb) bsums[t] = tmp[t] - v;
}

__global__ __launch_bounds__(256) void k_scanC(int* __restrict__ row_ptr,
                                               int* __restrict__ cursor,
                                               const int* __restrict__ bsums) {
  int t = threadIdx.x;
  int base = blockIdx.x * 1024 + t * 4;
  int off = bsums[blockIdx.x];
#pragma unroll
  for (int i = 0; i < 4; i++) {
    int idx = base + i;
    if (idx < NN) {
      int v = row_ptr[idx] + off;
      row_ptr[idx] = v;
      cursor[idx] = v;
    }
  }
  if (blockIdx.x == 0 && t == 0) row_ptr[NN] = EE;
}

__global__ __launch_bounds__(256) void k_scatter(const int* __restrict__ ei,
                                                 int* __restrict__ cursor,
                                                 int* __restrict__ col) {
  int e = blockIdx.x * 256 + threadIdx.x;
  if (e < EE) {
    int s = ei[e];
    int d = ei[EE + e];
    int pos = atomicAdd(&cursor[d], 1);
    col[pos] = s;
  }
}

// G = dinv .* (X @ W).  128 nodes/block, thread = 4 nodes x 4 feats.
// xs padded to stride 36 floats to break power-of-2 LDS row conflicts.
template <int K>
__global__ __launch_bounds__(256) void k_gemm(const float* __restrict__ X,
                                              const float* __restrict__ W,
                                              const float* __restrict__ dinv,
                                              float* __restrict__ Gout) {
  __shared__ float Wl[K * HID];
  __shared__ float xs[128 * 36];
  int t = threadIdx.x;
  for (int i = t; i < K * HID; i += 256) Wl[i] = W[i];
  int node0 = blockIdx.x * 128;
  int ng = t >> 3, f4 = t & 7;
  float acc[4][4];
#pragma unroll
  for (int j = 0; j < 4; j++)
#pragma unroll
    for (int c = 0; c < 4; c++) acc[j][c] = 0.f;

  for (int kc = 0; kc < K; kc += 32) {
    __syncthreads();
#pragma unroll
    for (int j = 0; j < 4; j++) {
      int idx = t + 256 * j;  // 1024 float4 slots = 128 rows x 8
      int r = idx >> 3, c4 = idx & 7;
      int row = node0 + r;
      if (row >= NN) row = NN - 1;
      float4 v = *reinterpret_cast<const float4*>(&X[(size_t)row * K + kc + c4 * 4]);
      *reinterpret_cast<float4*>(&xs[r * 36 + c4 * 4]) = v;
    }
    __syncthreads();
#pragma unroll
    for (int k4 = 0; k4 < 8; k4++) {
      float4 xv[4];
#pragma unroll
      for (int j = 0; j < 4; j++)
        xv[j] = *reinterpret_cast<const float4*>(&xs[(ng * 4 + j) * 36 + k4 * 4]);
#pragma unroll
      for (int kk = 0; kk < 4; kk++) {
        float4 wv = *reinterpret_cast<const float4*>(&Wl[(kc + k4 * 4 + kk) * HID + f4 * 4]);
#pragma unroll
        for (int j = 0; j < 4; j++) {
          float xvj = (kk == 0) ? xv[j].x : (kk == 1) ? xv[j].y : (kk == 2) ? xv[j].z : xv[j].w;
          acc[j][0] += xvj * wv.x;
          acc[j][1] += xvj * wv.y;
          acc[j][2] += xvj * wv.z;
          acc[j][3] += xvj * wv.w;
        }
      }
    }
  }
#pragma unroll
  for (int j = 0; j < 4; j++) {
    int node = node0 + ng * 4 + j;
    if (node < NN) {
      float s = dinv[node];
      float4 o;
      o.x = acc[j][0] * s;
      o.y = acc[j][1] * s;
      o.z = acc[j][2] * s;
      o.w = acc[j][3] * s;
      *reinterpret_cast<float4*>(&Gout[(size_t)node * HID + f4 * 4]) = o;
    }
  }
}

// X'[n] = act(dinv[n] * (sum_{in-edges} G[src] + G[n]) + b). 32 lanes = feats.
__global__ __launch_bounds__(256) void k_agg(const float* __restrict__ Gin,
                                             const int* __restrict__ col,
                                             const int* __restrict__ row_ptr,
                                             const float* __restrict__ dinv,
                                             const float* __restrict__ bias,
                                             float* __restrict__ Xout, int relu) {
  int t = threadIdx.x;
  int f = t & 31;
  int n = blockIdx.x * 8 + (t >> 5);
  int beg = row_ptr[n], end = row_ptr[n + 1];
  float acc = Gin[(size_t)n * HID + f];  // self-loop term
  for (int i = beg; i < end; i++) {
    int s = col[i];
    acc += Gin[(size_t)s * HID + f];
  }
  float v = dinv[n] * acc + bias[f];
  if (relu) v = fmaxf(v, 0.f);
  Xout[(size_t)n * HID + f] = v;
}

// Mean-pool: batch is sorted, so flush-on-graph-change keeps atomics rare.
__global__ __launch_bounds__(256) void k_pool(const float* __restrict__ X,
                                              const int* __restrict__ batch,
                                              float* __restrict__ sums,
                                              int* __restrict__ counts) {
  int t = threadIdx.x;
  int f = t & 31, slot = t >> 5;
  int base = blockIdx.x * 512;
  float acc = 0.f;
  int cnt = 0, cur = -1;
  for (int i = 0; i < 64; i++) {
    int n = base + slot + i * 8;
    if (n >= NN) break;
    int g = batch[n];
    if (g != cur) {
      if (cur >= 0) {
        atomicAdd(&sums[cur * HID + f], acc);
        if (f == 0) atomicAdd(&counts[cur], cnt);
      }
      cur = g;
      acc = 0.f;
      cnt = 0;
    }
    acc += X[(size_t)n * HID + f];
    cnt++;
  }
  if (cur >= 0) {
    atomicAdd(&sums[cur * HID + f], acc);
    if (f == 0) atomicAdd(&counts[cur], cnt);
  }
}

__global__ void k_fc(const float* __restrict__ sums, const int* __restrict__ counts,
                     const float* __restrict__ Wfc, const float* __restrict__ bfc,
                     float* __restrict__ out) {
  int idx = blockIdx.x * 256 + threadIdx.x;
  if (idx >= NGR * NC) return;
  int g = idx / NC, c = idx % NC;
  float inv = 1.f / fmaxf((float)counts[g], 1.f);
  float acc = bfc[c];
#pragma unroll
  for (int k = 0; k < HID; k++) acc += sums[g * HID + k] * inv * Wfc[k * NC + c];
  out[idx] = acc;
}

extern "C" void kernel_launch(void* const* d_in, const int* in_sizes, int n_in,
                              void* d_out, int out_size, void* d_ws, size_t ws_size,
                              hipStream_t stream) {
  (void)in_sizes; (void)n_in; (void)out_size; (void)ws_size;
  const float* x = (const float*)d_in[0];
  const int* ei = (const int*)d_in[1];
  const int* batch = (const int*)d_in[2];
  const float* W1 = (const float*)d_in[3];
  const float* b1 = (const float*)d_in[4];
  const float* W2 = (const float*)d_in[5];
  const float* b2 = (const float*)d_in[6];
  const float* W3 = (const float*)d_in[7];
  const float* b3 = (const float*)d_in[8];
  const float* Wfc = (const float*)d_in[9];
  const float* bfc = (const float*)d_in[10];
  float* out = (float*)d_out;

  char* ws = (char*)d_ws;
  size_t off = 0;
  auto alloc = [&](size_t bytes) -> void* {
    void* p = ws + off;
    off = (off + bytes + 255) & ~(size_t)255;
    return p;
  };
  float* dinv = (float*)alloc((size_t)NN * 4);
  int* deg = (int*)alloc((size_t)NN * 4);
  int* row_ptr = (int*)alloc((size_t)(NN + 1) * 4);
  int* cursor = (int*)alloc((size_t)NN * 4);
  int* bsums = (int*)alloc(256 * 4);
  int* col = (int*)alloc((size_t)EE * 4);
  float* Gbuf = (float*)alloc((size_t)NN * HID * 4);
  float* Abuf = (float*)alloc((size_t)NN * HID * 4);
  float* sums = (float*)alloc((size_t)NGR * HID * 4);
  int* counts = (int*)alloc((size_t)NGR * 4);

  hipMemsetAsync(deg, 0, (size_t)NN * 4, stream);
  hipMemsetAsync(sums, 0, (size_t)NGR * HID * 4, stream);
  hipMemsetAsync(counts, 0, (size_t)NGR * 4, stream);

  const int* dst = ei + EE;
  k_count<<<EE / 256, 256, 0, stream>>>(dst, deg);
  k_dinv<<<(NN + 255) / 256, 256, 0, stream>>>(deg, dinv);
  int nb = (NN + 1023) / 1024;  // 98
  k_scanA<<<nb, 256, 0, stream>>>(deg, row_ptr, bsums);
  k_scanB<<<1, 256, 0, stream>>>(bsums, nb);
  k_scanC<<<nb, 256, 0, stream>>>(row_ptr, cursor, bsums);
  k_scatter<<<EE / 256, 256, 0, stream>>>(ei, cursor, col);

  k_gemm<FIN><<<(NN + 127) / 128, 256, 0, stream>>>(x, W1, dinv, Gbuf);
  k_agg<<<NN / 8, 256, 0, stream>>>(Gbuf, col, row_ptr, dinv, b1, Abuf, 1);
  k_gemm<HID><<<(NN + 127) / 128, 256, 0, stream>>>(Abuf, W2, dinv, Gbuf);
  k_agg<<<NN / 8, 256, 0, stream>>>(Gbuf, col, row_ptr, dinv, b2, Abuf, 1);
  k_gemm<HID><<<(NN + 127) / 128, 256, 0, stream>>>(Abuf, W3, dinv, Gbuf);
  k_agg<<<NN / 8, 256, 0, stream>>>(Gbuf, col, row_ptr, dinv, b3, Abuf, 0);

  k_pool<<<(NN + 511) / 512, 256, 0, stream>>>(Abuf, batch, sums, counts);
  k_fc<<<(NGR * NC + 255) / 256, 256, 0, stream>>>(sums, counts, Wfc, bfc, out);
}

// Round 2
// 922.838 us; speedup vs baseline: 1.1345x; 1.1345x over previous
//
#include <hip/hip_runtime.h>

// GCN: 3x GCNConv(sym-norm, self-loops) + ReLU, mean-pool per graph, FC.
// Strategy: fold dinv into per-layer G = dinv .* (X@W); build dst-CSR once
// per call (histogram + scan + XCD-blocked counting-sort scatter) so
// aggregation is atomic-free.
// R1: scatter was 280us with 194MB WRITE_SIZE (random 4B writes -> full-line
// writebacks). Now 8 dst-ranges of 12500 nodes (1.6MB col + 50KB cursor per
// range fits one XCD L2), range = blockIdx&7 to ride the round-robin
// blockIdx->XCD dispatch. dst re-read 8x but L3-resident.

#define NN 100000
#define EE 3200000
#define FIN 128
#define HID 32
#define NGR 256
#define NC 10
#define NRANGE 12500  // NN / 8
#define BPX 128       // blocks per dst-range group

__global__ __launch_bounds__(256) void k_count(const int* __restrict__ dst,
                                               int* __restrict__ deg) {
  int e = blockIdx.x * 256 + threadIdx.x;
  if (e < EE) atomicAdd(&deg[dst[e]], 1);
}

__global__ __launch_bounds__(256) void k_dinv(const int* __restrict__ deg,
                                              float* __restrict__ dinv) {
  int n = blockIdx.x * 256 + threadIdx.x;
  if (n < NN) dinv[n] = rsqrtf((float)(deg[n] + 1));  // +1 = self-loop
}

// Exclusive scan of deg -> row_ptr (3-kernel hierarchical scan).
__global__ __launch_bounds__(256) void k_scanA(const int* __restrict__ in,
                                               int* __restrict__ out,
                                               int* __restrict__ bsums) {
  __shared__ int tmp[256];
  int t = threadIdx.x;
  int base = blockIdx.x * 1024 + t * 4;
  int v[4];
#pragma unroll
  for (int i = 0; i < 4; i++) v[i] = (base + i < NN) ? in[base + i] : 0;
  int s = v[0] + v[1] + v[2] + v[3];
  tmp[t] = s;
  __syncthreads();
#pragma unroll
  for (int off = 1; off < 256; off <<= 1) {
    int x = (t >= off) ? tmp[t - off] : 0;
    __syncthreads();
    tmp[t] += x;
    __syncthreads();
  }
  int excl = tmp[t] - s;
#pragma unroll
  for (int i = 0; i < 4; i++) {
    if (base + i < NN) out[base + i] = excl;
    excl += v[i];
  }
  if (t == 255) bsums[blockIdx.x] = tmp[255];
}

__global__ void k_scanB(int* __restrict__ bsums, int nb) {
  __shared__ int tmp[256];
  int t = threadIdx.x;
  int v = (t < nb) ? bsums[t] : 0;
  tmp[t] = v;
  __syncthreads();
  for (int off = 1; off < 256; off <<= 1) {
    int x = (t >= off) ? tmp[t - off] : 0;
    __syncthreads();
    tmp[t] += x;
    __syncthreads();
  }
  if (t < nb) bsums[t] = tmp[t] - v;
}

__global__ __launch_bounds__(256) void k_scanC(int* __restrict__ row_ptr,
                                               int* __restrict__ cursor,
                                               const int* __restrict__ bsums) {
  int t = threadIdx.x;
  int base = blockIdx.x * 1024 + t * 4;
  int off = bsums[blockIdx.x];
#pragma unroll
  for (int i = 0; i < 4; i++) {
    int idx = base + i;
    if (idx < NN) {
      int v = row_ptr[idx] + off;
      row_ptr[idx] = v;
      cursor[idx] = v;
    }
  }
  if (blockIdx.x == 0 && t == 0) row_ptr[NN] = EE;
}

// XCD-blocked scatter: range r = blockIdx&7 handles dst in [r*12500,(r+1)*12500).
// col/cursor slice for one range fits in a single XCD's 4MB L2, so each 64B
// col line accumulates all 16 entries before writeback.
__global__ __launch_bounds__(256) void k_scatter_x(const int* __restrict__ ei,
                                                   int* __restrict__ cursor,
                                                   int* __restrict__ col) {
  int r = blockIdx.x & 7;
  int grp = blockIdx.x >> 3;  // 0..BPX-1
  int lo = r * NRANGE, hi = lo + NRANGE;
  const int* dst = ei + EE;
  for (int e = grp * 256 + threadIdx.x; e < EE; e += BPX * 256) {
    int d = dst[e];
    if (d >= lo && d < hi) {
      int pos = atomicAdd(&cursor[d], 1);
      col[pos] = ei[e];
    }
  }
}

// G = dinv .* (X @ W).  128 nodes/block, thread = 4 nodes x 4 feats.
// xs padded to stride 36 floats to break power-of-2 LDS row conflicts.
template <int K>
__global__ __launch_bounds__(256) void k_gemm(const float* __restrict__ X,
                                              const float* __restrict__ W,
                                              const float* __restrict__ dinv,
                                              float* __restrict__ Gout) {
  __shared__ float Wl[K * HID];
  __shared__ float xs[128 * 36];
  int t = threadIdx.x;
  for (int i = t; i < K * HID; i += 256) Wl[i] = W[i];
  int node0 = blockIdx.x * 128;
  int ng = t >> 3, f4 = t & 7;
  float acc[4][4];
#pragma unroll
  for (int j = 0; j < 4; j++)
#pragma unroll
    for (int c = 0; c < 4; c++) acc[j][c] = 0.f;

  for (int kc = 0; kc < K; kc += 32) {
    __syncthreads();
#pragma unroll
    for (int j = 0; j < 4; j++) {
      int idx = t + 256 * j;  // 1024 float4 slots = 128 rows x 8
      int r = idx >> 3, c4 = idx & 7;
      int row = node0 + r;
      if (row >= NN) row = NN - 1;
      float4 v = *reinterpret_cast<const float4*>(&X[(size_t)row * K + kc + c4 * 4]);
      *reinterpret_cast<float4*>(&xs[r * 36 + c4 * 4]) = v;
    }
    __syncthreads();
#pragma unroll
    for (int k4 = 0; k4 < 8; k4++) {
      float4 xv[4];
#pragma unroll
      for (int j = 0; j < 4; j++)
        xv[j] = *reinterpret_cast<const float4*>(&xs[(ng * 4 + j) * 36 + k4 * 4]);
#pragma unroll
      for (int kk = 0; kk < 4; kk++) {
        float4 wv = *reinterpret_cast<const float4*>(&Wl[(kc + k4 * 4 + kk) * HID + f4 * 4]);
#pragma unroll
        for (int j = 0; j < 4; j++) {
          float xvj = (kk == 0) ? xv[j].x : (kk == 1) ? xv[j].y : (kk == 2) ? xv[j].z : xv[j].w;
          acc[j][0] += xvj * wv.x;
          acc[j][1] += xvj * wv.y;
          acc[j][2] += xvj * wv.z;
          acc[j][3] += xvj * wv.w;
        }
      }
    }
  }
#pragma unroll
  for (int j = 0; j < 4; j++) {
    int node = node0 + ng * 4 + j;
    if (node < NN) {
      float s = dinv[node];
      float4 o;
      o.x = acc[j][0] * s;
      o.y = acc[j][1] * s;
      o.z = acc[j][2] * s;
      o.w = acc[j][3] * s;
      *reinterpret_cast<float4*>(&Gout[(size_t)node * HID + f4 * 4]) = o;
    }
  }
}

// X'[n] = act(dinv[n] * (sum_{in-edges} G[src] + G[n]) + b). 32 lanes = feats.
__global__ __launch_bounds__(256) void k_agg(const float* __restrict__ Gin,
                                             const int* __restrict__ col,
                                             const int* __restrict__ row_ptr,
                                             const float* __restrict__ dinv,
                                             const float* __restrict__ bias,
                                             float* __restrict__ Xout, int relu) {
  int t = threadIdx.x;
  int f = t & 31;
  int n = blockIdx.x * 8 + (t >> 5);
  int beg = row_ptr[n], end = row_ptr[n + 1];
  float acc = Gin[(size_t)n * HID + f];  // self-loop term
  for (int i = beg; i < end; i++) {
    int s = col[i];
    acc += Gin[(size_t)s * HID + f];
  }
  float v = dinv[n] * acc + bias[f];
  if (relu) v = fmaxf(v, 0.f);
  Xout[(size_t)n * HID + f] = v;
}

// Mean-pool: batch is sorted, so flush-on-graph-change keeps atomics rare.
__global__ __launch_bounds__(256) void k_pool(const float* __restrict__ X,
                                              const int* __restrict__ batch,
                                              float* __restrict__ sums,
                                              int* __restrict__ counts) {
  int t = threadIdx.x;
  int f = t & 31, slot = t >> 5;
  int base = blockIdx.x * 512;
  float acc = 0.f;
  int cnt = 0, cur = -1;
  for (int i = 0; i < 64; i++) {
    int n = base + slot + i * 8;
    if (n >= NN) break;
    int g = batch[n];
    if (g != cur) {
      if (cur >= 0) {
        atomicAdd(&sums[cur * HID + f], acc);
        if (f == 0) atomicAdd(&counts[cur], cnt);
      }
      cur = g;
      acc = 0.f;
      cnt = 0;
    }
    acc += X[(size_t)n * HID + f];
    cnt++;
  }
  if (cur >= 0) {
    atomicAdd(&sums[cur * HID + f], acc);
    if (f == 0) atomicAdd(&counts[cur], cnt);
  }
}

__global__ void k_fc(const float* __restrict__ sums, const int* __restrict__ counts,
                     const float* __restrict__ Wfc, const float* __restrict__ bfc,
                     float* __restrict__ out) {
  int idx = blockIdx.x * 256 + threadIdx.x;
  if (idx >= NGR * NC) return;
  int g = idx / NC, c = idx % NC;
  float inv = 1.f / fmaxf((float)counts[g], 1.f);
  float acc = bfc[c];
#pragma unroll
  for (int k = 0; k < HID; k++) acc += sums[g * HID + k] * inv * Wfc[k * NC + c];
  out[idx] = acc;
}

extern "C" void kernel_launch(void* const* d_in, const int* in_sizes, int n_in,
                              void* d_out, int out_size, void* d_ws, size_t ws_size,
                              hipStream_t stream) {
  (void)in_sizes; (void)n_in; (void)out_size; (void)ws_size;
  const float* x = (const float*)d_in[0];
  const int* ei = (const int*)d_in[1];
  const int* batch = (const int*)d_in[2];
  const float* W1 = (const float*)d_in[3];
  const float* b1 = (const float*)d_in[4];
  const float* W2 = (const float*)d_in[5];
  const float* b2 = (const float*)d_in[6];
  const float* W3 = (const float*)d_in[7];
  const float* b3 = (const float*)d_in[8];
  const float* Wfc = (const float*)d_in[9];
  const float* bfc = (const float*)d_in[10];
  float* out = (float*)d_out;

  char* ws = (char*)d_ws;
  size_t off = 0;
  auto alloc = [&](size_t bytes) -> void* {
    void* p = ws + off;
    off = (off + bytes + 255) & ~(size_t)255;
    return p;
  };
  float* dinv = (float*)alloc((size_t)NN * 4);
  int* deg = (int*)alloc((size_t)NN * 4);
  int* row_ptr = (int*)alloc((size_t)(NN + 1) * 4);
  int* cursor = (int*)alloc((size_t)NN * 4);
  int* bsums = (int*)alloc(256 * 4);
  int* col = (int*)alloc((size_t)EE * 4);
  float* Gbuf = (float*)alloc((size_t)NN * HID * 4);
  float* Abuf = (float*)alloc((size_t)NN * HID * 4);
  float* sums = (float*)alloc((size_t)NGR * HID * 4);
  int* counts = (int*)alloc((size_t)NGR * 4);

  hipMemsetAsync(deg, 0, (size_t)NN * 4, stream);
  hipMemsetAsync(sums, 0, (size_t)NGR * HID * 4, stream);
  hipMemsetAsync(counts, 0, (size_t)NGR * 4, stream);

  const int* dst = ei + EE;
  k_count<<<EE / 256, 256, 0, stream>>>(dst, deg);
  k_dinv<<<(NN + 255) / 256, 256, 0, stream>>>(deg, dinv);
  int nb = (NN + 1023) / 1024;  // 98
  k_scanA<<<nb, 256, 0, stream>>>(deg, row_ptr, bsums);
  k_scanB<<<1, 256, 0, stream>>>(bsums, nb);
  k_scanC<<<nb, 256, 0, stream>>>(row_ptr, cursor, bsums);
  k_scatter_x<<<BPX * 8, 256, 0, stream>>>(ei, cursor, col);

  k_gemm<FIN><<<(NN + 127) / 128, 256, 0, stream>>>(x, W1, dinv, Gbuf);
  k_agg<<<NN / 8, 256, 0, stream>>>(Gbuf, col, row_ptr, dinv, b1, Abuf, 1);
  k_gemm<HID><<<(NN + 127) / 128, 256, 0, stream>>>(Abuf, W2, dinv, Gbuf);
  k_agg<<<NN / 8, 256, 0, stream>>>(Gbuf, col, row_ptr, dinv, b2, Abuf, 1);
  k_gemm<HID><<<(NN + 127) / 128, 256, 0, stream>>>(Abuf, W3, dinv, Gbuf);
  k_agg<<<NN / 8, 256, 0, stream>>>(Gbuf, col, row_ptr, dinv, b3, Abuf, 0);

  k_pool<<<(NN + 511) / 512, 256, 0, stream>>>(Abuf, batch, sums, counts);
  k_fc<<<(NGR * NC + 255) / 256, 256, 0, stream>>>(sums, counts, Wfc, bfc, out);
}

// Round 3
// 674.284 us; speedup vs baseline: 1.5526x; 1.3686x over previous
//
#include <hip/hip_runtime.h>

// GCN: 3x GCNConv(sym-norm, self-loops) + ReLU, mean-pool per graph, FC.
// Strategy: fold dinv into per-layer G = dinv .* (X@W); build dst-CSR once
// per call (histogram + scan + XCD-blocked counting-sort scatter) so
// aggregation is atomic-free.
// R1: scatter 280us, 194MB WRITE (random 4B writes -> full-line writebacks).
// R2: XCD-blocked scatter -> 170us, but WRITE stayed 174MB: the 8x dst/src
//     read streams evicted the col slice from L2. k_agg (3x152us) is
//     latency-bound (VALUBusy 13.6%, ~1.1TB/s).
// R3: (a) nontemporal dst/src loads in scatter so col/cursor stay L2-resident;
//     (b) k_agg restructured: 16 lanes x float2 per node, 8x unroll into 8
//     independent accumulators -> 8 outstanding gathers per slot; nt col reads.

#define NN 100000
#define EE 3200000
#define FIN 128
#define HID 32
#define NGR 256
#define NC 10
#define NRANGE 12500  // NN / 8
#define BPX 128       // blocks per dst-range group

__global__ __launch_bounds__(256) void k_count(const int* __restrict__ dst,
                                               int* __restrict__ deg) {
  int e = blockIdx.x * 256 + threadIdx.x;
  if (e < EE) atomicAdd(&deg[dst[e]], 1);
}

__global__ __launch_bounds__(256) void k_dinv(const int* __restrict__ deg,
                                              float* __restrict__ dinv) {
  int n = blockIdx.x * 256 + threadIdx.x;
  if (n < NN) dinv[n] = rsqrtf((float)(deg[n] + 1));  // +1 = self-loop
}

// Exclusive scan of deg -> row_ptr (3-kernel hierarchical scan).
__global__ __launch_bounds__(256) void k_scanA(const int* __restrict__ in,
                                               int* __restrict__ out,
                                               int* __restrict__ bsums) {
  __shared__ int tmp[256];
  int t = threadIdx.x;
  int base = blockIdx.x * 1024 + t * 4;
  int v[4];
#pragma unroll
  for (int i = 0; i < 4; i++) v[i] = (base + i < NN) ? in[base + i] : 0;
  int s = v[0] + v[1] + v[2] + v[3];
  tmp[t] = s;
  __syncthreads();
#pragma unroll
  for (int off = 1; off < 256; off <<= 1) {
    int x = (t >= off) ? tmp[t - off] : 0;
    __syncthreads();
    tmp[t] += x;
    __syncthreads();
  }
  int excl = tmp[t] - s;
#pragma unroll
  for (int i = 0; i < 4; i++) {
    if (base + i < NN) out[base + i] = excl;
    excl += v[i];
  }
  if (t == 255) bsums[blockIdx.x] = tmp[255];
}

__global__ void k_scanB(int* __restrict__ bsums, int nb) {
  __shared__ int tmp[256];
  int t = threadIdx.x;
  int v = (t < nb) ? bsums[t] : 0;
  tmp[t] = v;
  __syncthreads();
  for (int off = 1; off < 256; off <<= 1) {
    int x = (t >= off) ? tmp[t - off] : 0;
    __syncthreads();
    tmp[t] += x;
    __syncthreads();
  }
  if (t < nb) bsums[t] = tmp[t] - v;
}

__global__ __launch_bounds__(256) void k_scanC(int* __restrict__ row_ptr,
                                               int* __restrict__ cursor,
                                               const int* __restrict__ bsums) {
  int t = threadIdx.x;
  int base = blockIdx.x * 1024 + t * 4;
  int off = bsums[blockIdx.x];
#pragma unroll
  for (int i = 0; i < 4; i++) {
    int idx = base + i;
    if (idx < NN) {
      int v = row_ptr[idx] + off;
      row_ptr[idx] = v;
      cursor[idx] = v;
    }
  }
  if (blockIdx.x == 0 && t == 0) row_ptr[NN] = EE;
}

// XCD-blocked scatter: range r = blockIdx&7 handles dst in [r*12500,(r+1)*12500).
// col/cursor slice for one range fits in a single XCD's 4MB L2. dst/src read
// streams are nontemporal (evict-first) so they don't evict the col slice.
__global__ __launch_bounds__(256) void k_scatter_x(const int* __restrict__ ei,
                                                   int* __restrict__ cursor,
                                                   int* __restrict__ col) {
  int r = blockIdx.x & 7;
  int grp = blockIdx.x >> 3;  // 0..BPX-1
  int lo = r * NRANGE, hi = lo + NRANGE;
  const int* dst = ei + EE;
  for (int e = grp * 256 + threadIdx.x; e < EE; e += BPX * 256) {
    int d = __builtin_nontemporal_load(&dst[e]);
    if (d >= lo && d < hi) {
      int s = __builtin_nontemporal_load(&ei[e]);
      int pos = atomicAdd(&cursor[d], 1);
      col[pos] = s;
    }
  }
}

// G = dinv .* (X @ W).  128 nodes/block, thread = 4 nodes x 4 feats.
// xs padded to stride 36 floats to break power-of-2 LDS row conflicts.
template <int K>
__global__ __launch_bounds__(256) void k_gemm(const float* __restrict__ X,
                                              const float* __restrict__ W,
                                              const float* __restrict__ dinv,
                                              float* __restrict__ Gout) {
  __shared__ float Wl[K * HID];
  __shared__ float xs[128 * 36];
  int t = threadIdx.x;
  for (int i = t; i < K * HID; i += 256) Wl[i] = W[i];
  int node0 = blockIdx.x * 128;
  int ng = t >> 3, f4 = t & 7;
  float acc[4][4];
#pragma unroll
  for (int j = 0; j < 4; j++)
#pragma unroll
    for (int c = 0; c < 4; c++) acc[j][c] = 0.f;

  for (int kc = 0; kc < K; kc += 32) {
    __syncthreads();
#pragma unroll
    for (int j = 0; j < 4; j++) {
      int idx = t + 256 * j;  // 1024 float4 slots = 128 rows x 8
      int r = idx >> 3, c4 = idx & 7;
      int row = node0 + r;
      if (row >= NN) row = NN - 1;
      float4 v = *reinterpret_cast<const float4*>(&X[(size_t)row * K + kc + c4 * 4]);
      *reinterpret_cast<float4*>(&xs[r * 36 + c4 * 4]) = v;
    }
    __syncthreads();
#pragma unroll
    for (int k4 = 0; k4 < 8; k4++) {
      float4 xv[4];
#pragma unroll
      for (int j = 0; j < 4; j++)
        xv[j] = *reinterpret_cast<const float4*>(&xs[(ng * 4 + j) * 36 + k4 * 4]);
#pragma unroll
      for (int kk = 0; kk < 4; kk++) {
        float4 wv = *reinterpret_cast<const float4*>(&Wl[(kc + k4 * 4 + kk) * HID + f4 * 4]);
#pragma unroll
        for (int j = 0; j < 4; j++) {
          float xvj = (kk == 0) ? xv[j].x : (kk == 1) ? xv[j].y : (kk == 2) ? xv[j].z : xv[j].w;
          acc[j][0] += xvj * wv.x;
          acc[j][1] += xvj * wv.y;
          acc[j][2] += xvj * wv.z;
          acc[j][3] += xvj * wv.w;
        }
      }
    }
  }
#pragma unroll
  for (int j = 0; j < 4; j++) {
    int node = node0 + ng * 4 + j;
    if (node < NN) {
      float s = dinv[node];
      float4 o;
      o.x = acc[j][0] * s;
      o.y = acc[j][1] * s;
      o.z = acc[j][2] * s;
      o.w = acc[j][3] * s;
      *reinterpret_cast<float4*>(&Gout[(size_t)node * HID + f4 * 4]) = o;
    }
  }
}

// X'[n] = act(dinv[n] * (sum_{in-edges} G[src] + G[n]) + b).
// 16 lanes x float2 per node (4 nodes/wave, 16 nodes/block); 8x unrolled
// into 8 independent accumulators for 8 outstanding gathers per slot.
__global__ __launch_bounds__(256) void k_agg(const float* __restrict__ Gin,
                                             const int* __restrict__ col,
                                             const int* __restrict__ row_ptr,
                                             const float* __restrict__ dinv,
                                             const float* __restrict__ bias,
                                             float* __restrict__ Xout, int relu) {
  const float2* G2 = reinterpret_cast<const float2*>(Gin);
  int t = threadIdx.x;
  int h = t & 15;          // float2 index within row (feats 2h, 2h+1)
  int slot = t >> 4;       // 0..15 node slot within block
  int n = blockIdx.x * 16 + slot;
  int beg = row_ptr[n], end = row_ptr[n + 1];

  float2 a0 = G2[(size_t)n * 16 + h];  // self-loop term
  float2 a1 = {0.f, 0.f}, a2 = {0.f, 0.f}, a3 = {0.f, 0.f};
  float2 a4 = {0.f, 0.f}, a5 = {0.f, 0.f}, a6 = {0.f, 0.f}, a7 = {0.f, 0.f};

  int i = beg;
  for (; i + 8 <= end; i += 8) {
    int s0 = __builtin_nontemporal_load(&col[i + 0]);
    int s1 = __builtin_nontemporal_load(&col[i + 1]);
    int s2 = __builtin_nontemporal_load(&col[i + 2]);
    int s3 = __builtin_nontemporal_load(&col[i + 3]);
    int s4 = __builtin_nontemporal_load(&col[i + 4]);
    int s5 = __builtin_nontemporal_load(&col[i + 5]);
    int s6 = __builtin_nontemporal_load(&col[i + 6]);
    int s7 = __builtin_nontemporal_load(&col[i + 7]);
    float2 g0 = G2[(size_t)s0 * 16 + h];
    float2 g1 = G2[(size_t)s1 * 16 + h];
    float2 g2 = G2[(size_t)s2 * 16 + h];
    float2 g3 = G2[(size_t)s3 * 16 + h];
    float2 g4 = G2[(size_t)s4 * 16 + h];
    float2 g5 = G2[(size_t)s5 * 16 + h];
    float2 g6 = G2[(size_t)s6 * 16 + h];
    float2 g7 = G2[(size_t)s7 * 16 + h];
    a0.x += g0.x; a0.y += g0.y;
    a1.x += g1.x; a1.y += g1.y;
    a2.x += g2.x; a2.y += g2.y;
    a3.x += g3.x; a3.y += g3.y;
    a4.x += g4.x; a4.y += g4.y;
    a5.x += g5.x; a5.y += g5.y;
    a6.x += g6.x; a6.y += g6.y;
    a7.x += g7.x; a7.y += g7.y;
  }
  for (; i < end; i++) {
    int s = __builtin_nontemporal_load(&col[i]);
    float2 g = G2[(size_t)s * 16 + h];
    a0.x += g.x; a0.y += g.y;
  }
  a0.x += a1.x + a2.x + a3.x + a4.x + a5.x + a6.x + a7.x;
  a0.y += a1.y + a2.y + a3.y + a4.y + a5.y + a6.y + a7.y;

  float s = dinv[n];
  float2 b = reinterpret_cast<const float2*>(bias)[h];
  float2 v;
  v.x = s * a0.x + b.x;
  v.y = s * a0.y + b.y;
  if (relu) {
    v.x = fmaxf(v.x, 0.f);
    v.y = fmaxf(v.y, 0.f);
  }
  reinterpret_cast<float2*>(Xout)[(size_t)n * 16 + h] = v;
}

// Mean-pool: batch is sorted, so flush-on-graph-change keeps atomics rare.
__global__ __launch_bounds__(256) void k_pool(const float* __restrict__ X,
                                              const int* __restrict__ batch,
                                              float* __restrict__ sums,
                                              int* __restrict__ counts) {
  int t = threadIdx.x;
  int f = t & 31, slot = t >> 5;
  int base = blockIdx.x * 512;
  float acc = 0.f;
  int cnt = 0, cur = -1;
  for (int i = 0; i < 64; i++) {
    int n = base + slot + i * 8;
    if (n >= NN) break;
    int g = batch[n];
    if (g != cur) {
      if (cur >= 0) {
        atomicAdd(&sums[cur * HID + f], acc);
        if (f == 0) atomicAdd(&counts[cur], cnt);
      }
      cur = g;
      acc = 0.f;
      cnt = 0;
    }
    acc += X[(size_t)n * HID + f];
    cnt++;
  }
  if (cur >= 0) {
    atomicAdd(&sums[cur * HID + f], acc);
    if (f == 0) atomicAdd(&counts[cur], cnt);
  }
}

__global__ void k_fc(const float* __restrict__ sums, const int* __restrict__ counts,
                     const float* __restrict__ Wfc, const float* __restrict__ bfc,
                     float* __restrict__ out) {
  int idx = blockIdx.x * 256 + threadIdx.x;
  if (idx >= NGR * NC) return;
  int g = idx / NC, c = idx % NC;
  float inv = 1.f / fmaxf((float)counts[g], 1.f);
  float acc = bfc[c];
#pragma unroll
  for (int k = 0; k < HID; k++) acc += sums[g * HID + k] * inv * Wfc[k * NC + c];
  out[idx] = acc;
}

extern "C" void kernel_launch(void* const* d_in, const int* in_sizes, int n_in,
                              void* d_out, int out_size, void* d_ws, size_t ws_size,
                              hipStream_t stream) {
  (void)in_sizes; (void)n_in; (void)out_size; (void)ws_size;
  const float* x = (const float*)d_in[0];
  const int* ei = (const int*)d_in[1];
  const int* batch = (const int*)d_in[2];
  const float* W1 = (const float*)d_in[3];
  const float* b1 = (const float*)d_in[4];
  const float* W2 = (const float*)d_in[5];
  const float* b2 = (const float*)d_in[6];
  const float* W3 = (const float*)d_in[7];
  const float* b3 = (const float*)d_in[8];
  const float* Wfc = (const float*)d_in[9];
  const float* bfc = (const float*)d_in[10];
  float* out = (float*)d_out;

  char* ws = (char*)d_ws;
  size_t off = 0;
  auto alloc = [&](size_t bytes) -> void* {
    void* p = ws + off;
    off = (off + bytes + 255) & ~(size_t)255;
    return p;
  };
  float* dinv = (float*)alloc((size_t)NN * 4);
  int* deg = (int*)alloc((size_t)NN * 4);
  int* row_ptr = (int*)alloc((size_t)(NN + 1) * 4);
  int* cursor = (int*)alloc((size_t)NN * 4);
  int* bsums = (int*)alloc(256 * 4);
  int* col = (int*)alloc((size_t)EE * 4);
  float* Gbuf = (float*)alloc((size_t)NN * HID * 4);
  float* Abuf = (float*)alloc((size_t)NN * HID * 4);
  float* sums = (float*)alloc((size_t)NGR * HID * 4);
  int* counts = (int*)alloc((size_t)NGR * 4);

  hipMemsetAsync(deg, 0, (size_t)NN * 4, stream);
  hipMemsetAsync(sums, 0, (size_t)NGR * HID * 4, stream);
  hipMemsetAsync(counts, 0, (size_t)NGR * 4, stream);

  const int* dst = ei + EE;
  k_count<<<EE / 256, 256, 0, stream>>>(dst, deg);
  k_dinv<<<(NN + 255) / 256, 256, 0, stream>>>(deg, dinv);
  int nb = (NN + 1023) / 1024;  // 98
  k_scanA<<<nb, 256, 0, stream>>>(deg, row_ptr, bsums);
  k_scanB<<<1, 256, 0, stream>>>(bsums, nb);
  k_scanC<<<nb, 256, 0, stream>>>(row_ptr, cursor, bsums);
  k_scatter_x<<<BPX * 8, 256, 0, stream>>>(ei, cursor, col);

  k_gemm<FIN><<<(NN + 127) / 128, 256, 0, stream>>>(x, W1, dinv, Gbuf);
  k_agg<<<NN / 16, 256, 0, stream>>>(Gbuf, col, row_ptr, dinv, b1, Abuf, 1);
  k_gemm<HID><<<(NN + 127) / 128, 256, 0, stream>>>(Abuf, W2, dinv, Gbuf);
  k_agg<<<NN / 16, 256, 0, stream>>>(Gbuf, col, row_ptr, dinv, b2, Abuf, 1);
  k_gemm<HID><<<(NN + 127) / 128, 256, 0, stream>>>(Abuf, W3, dinv, Gbuf);
  k_agg<<<NN / 16, 256, 0, stream>>>(Gbuf, col, row_ptr, dinv, b3, Abuf, 0);

  k_pool<<<(NN + 511) / 512, 256, 0, stream>>>(Abuf, batch, sums, counts);
  k_fc<<<(NGR * NC + 255) / 256, 256, 0, stream>>>(sums, counts, Wfc, bfc, out);
}

// Round 4
// 647.357 us; speedup vs baseline: 1.6172x; 1.0416x over previous
//
#include <hip/hip_runtime.h>

// GCN: 3x GCNConv(sym-norm, self-loops) + ReLU, mean-pool per graph, FC.
// Strategy: fold dinv into per-layer G = dinv .* (X@W); build dst-CSR once
// per call so aggregation is atomic-free.
// R1: scatter 280us, 194MB WRITE (random 4B writes -> full-line writebacks).
// R2: XCD-blocked scatter -> 170us; WRITE stayed 174MB (read streams evict col).
// R3: nt loads + ILP'd k_agg -> 674us; agg fixed (off top-5) but scatter still
//     152us / 130MB WRITE: hot(1.6MB):stream(25.6MB) ratio too adverse.
// R4: two-pass bucketed counting sort. PassA bins edges into 128 dst-buckets
//     (coalesced ~390B runs, reads edges exactly 2x, fuses deg count).
//     PassB scatters within one 100KB bucket slice per block-group -> col
//     lines fill completely while L2-resident.

#define NN 100000
#define EE 3200000
#define FIN 128
#define HID 32
#define NGR 256
#define NC 10
#define NBUK 128
#define BRANGE 782    // 128*782 = 100096 >= NN
#define BSLACK 25800  // mean 25024, sd ~157 -> ~5 sigma slack (input is fixed)
#define SUBB 8        // blocks per bucket in PassB

__global__ void k_init(int* __restrict__ bcur) {
  int t = threadIdx.x;
  if (t < NBUK) bcur[t] = t * BSLACK;
}

__global__ __launch_bounds__(256) void k_dinv(const int* __restrict__ deg,
                                              float* __restrict__ dinv) {
  int n = blockIdx.x * 256 + threadIdx.x;
  if (n < NN) dinv[n] = rsqrtf((float)(deg[n] + 1));  // +1 = self-loop
}

// Pass A: bin edges by dst-bucket with LDS histogram + per-block run
// reservation; fused deg histogram. Each block owns 6250 contiguous edges.
__global__ __launch_bounds__(256) void k_bucket(const int* __restrict__ ei,
                                                int* __restrict__ deg,
                                                int* __restrict__ bcur,
                                                int2* __restrict__ bpair) {
  __shared__ int hist[NBUK];
  __shared__ int base[NBUK];
  int t = threadIdx.x;
  if (t < NBUK) hist[t] = 0;
  __syncthreads();
  const int* src = ei;
  const int* dst = ei + EE;
  int e0 = blockIdx.x * 6250;
  for (int i = t; i < 6250; i += 256) {
    int d = __builtin_nontemporal_load(&dst[e0 + i]);
    atomicAdd(&hist[d / BRANGE], 1);
    atomicAdd(&deg[d], 1);
  }
  __syncthreads();
  if (t < NBUK) {
    base[t] = atomicAdd(&bcur[t], hist[t]);
    hist[t] = 0;  // reuse as block-local cursor
  }
  __syncthreads();
  for (int i = t; i < 6250; i += 256) {
    int d = __builtin_nontemporal_load(&dst[e0 + i]);
    int s = __builtin_nontemporal_load(&src[e0 + i]);
    int q = d / BRANGE;
    int off = atomicAdd(&hist[q], 1);
    int2 p;
    p.x = s;
    p.y = d;
    bpair[(size_t)base[q] + off] = p;
  }
}

// Exclusive scan of deg -> row_ptr (3-kernel hierarchical scan).
__global__ __launch_bounds__(256) void k_scanA(const int* __restrict__ in,
                                               int* __restrict__ out,
                                               int* __restrict__ bsums) {
  __shared__ int tmp[256];
  int t = threadIdx.x;
  int base = blockIdx.x * 1024 + t * 4;
  int v[4];
#pragma unroll
  for (int i = 0; i < 4; i++) v[i] = (base + i < NN) ? in[base + i] : 0;
  int s = v[0] + v[1] + v[2] + v[3];
  tmp[t] = s;
  __syncthreads();
#pragma unroll
  for (int off = 1; off < 256; off <<= 1) {
    int x = (t >= off) ? tmp[t - off] : 0;
    __syncthreads();
    tmp[t] += x;
    __syncthreads();
  }
  int excl = tmp[t] - s;
#pragma unroll
  for (int i = 0; i < 4; i++) {
    if (base + i < NN) out[base + i] = excl;
    excl += v[i];
  }
  if (t == 255) bsums[blockIdx.x] = tmp[255];
}

__global__ void k_scanB(int* __restrict__ bsums, int nb) {
  __shared__ int tmp[256];
  int t = threadIdx.x;
  int v = (t < nb) ? bsums[t] : 0;
  tmp[t] = v;
  __syncthreads();
  for (int off = 1; off < 256; off <<= 1) {
    int x = (t >= off) ? tmp[t - off] : 0;
    __syncthreads();
    tmp[t] += x;
    __syncthreads();
  }
  if (t < nb) bsums[t] = tmp[t] - v;
}

__global__ __launch_bounds__(256) void k_scanC(int* __restrict__ row_ptr,
                                               int* __restrict__ cursor,
                                               const int* __restrict__ bsums) {
  int t = threadIdx.x;
  int base = blockIdx.x * 1024 + t * 4;
  int off = bsums[blockIdx.x];
#pragma unroll
  for (int i = 0; i < 4; i++) {
    int idx = base + i;
    if (idx < NN) {
      int v = row_ptr[idx] + off;
      row_ptr[idx] = v;
      cursor[idx] = v;
    }
  }
  if (blockIdx.x == 0 && t == 0) row_ptr[NN] = EE;
}

// Pass B: scatter within one bucket (100KB col slice, L2-resident).
// bucket = blockIdx&127 keeps XCD affinity (blockIdx&7 == bucket&7).
__global__ __launch_bounds__(256) void k_scatter_b(const int2* __restrict__ bpair,
                                                   const int* __restrict__ bcur,
                                                   int* __restrict__ cursor,
                                                   int* __restrict__ col) {
  int b = blockIdx.x & (NBUK - 1);
  int sub = blockIdx.x >> 7;
  int end = bcur[b];  // end position after PassA
  const int* ip = reinterpret_cast<const int*>(bpair);
  for (int e = b * BSLACK + sub * 256 + threadIdx.x; e < end; e += SUBB * 256) {
    int s = __builtin_nontemporal_load(&ip[2 * (size_t)e]);
    int d = __builtin_nontemporal_load(&ip[2 * (size_t)e + 1]);
    int pos = atomicAdd(&cursor[d], 1);
    col[pos] = s;
  }
}

// G = dinv .* (X @ W).  128 nodes/block, thread = 4 nodes x 4 feats.
// xs padded to stride 36 floats to break power-of-2 LDS row conflicts.
template <int K>
__global__ __launch_bounds__(256) void k_gemm(const float* __restrict__ X,
                                              const float* __restrict__ W,
                                              const float* __restrict__ dinv,
                                              float* __restrict__ Gout) {
  __shared__ float Wl[K * HID];
  __shared__ float xs[128 * 36];
  int t = threadIdx.x;
  for (int i = t; i < K * HID; i += 256) Wl[i] = W[i];
  int node0 = blockIdx.x * 128;
  int ng = t >> 3, f4 = t & 7;
  float acc[4][4];
#pragma unroll
  for (int j = 0; j < 4; j++)
#pragma unroll
    for (int c = 0; c < 4; c++) acc[j][c] = 0.f;

  for (int kc = 0; kc < K; kc += 32) {
    __syncthreads();
#pragma unroll
    for (int j = 0; j < 4; j++) {
      int idx = t + 256 * j;  // 1024 float4 slots = 128 rows x 8
      int r = idx >> 3, c4 = idx & 7;
      int row = node0 + r;
      if (row >= NN) row = NN - 1;
      float4 v = *reinterpret_cast<const float4*>(&X[(size_t)row * K + kc + c4 * 4]);
      *reinterpret_cast<float4*>(&xs[r * 36 + c4 * 4]) = v;
    }
    __syncthreads();
#pragma unroll
    for (int k4 = 0; k4 < 8; k4++) {
      float4 xv[4];
#pragma unroll
      for (int j = 0; j < 4; j++)
        xv[j] = *reinterpret_cast<const float4*>(&xs[(ng * 4 + j) * 36 + k4 * 4]);
#pragma unroll
      for (int kk = 0; kk < 4; kk++) {
        float4 wv = *reinterpret_cast<const float4*>(&Wl[(kc + k4 * 4 + kk) * HID + f4 * 4]);
#pragma unroll
        for (int j = 0; j < 4; j++) {
          float xvj = (kk == 0) ? xv[j].x : (kk == 1) ? xv[j].y : (kk == 2) ? xv[j].z : xv[j].w;
          acc[j][0] += xvj * wv.x;
          acc[j][1] += xvj * wv.y;
          acc[j][2] += xvj * wv.z;
          acc[j][3] += xvj * wv.w;
        }
      }
    }
  }
#pragma unroll
  for (int j = 0; j < 4; j++) {
    int node = node0 + ng * 4 + j;
    if (node < NN) {
      float s = dinv[node];
      float4 o;
      o.x = acc[j][0] * s;
      o.y = acc[j][1] * s;
      o.z = acc[j][2] * s;
      o.w = acc[j][3] * s;
      *reinterpret_cast<float4*>(&Gout[(size_t)node * HID + f4 * 4]) = o;
    }
  }
}

// X'[n] = act(dinv[n] * (sum_{in-edges} G[src] + G[n]) + b).
// 16 lanes x float2 per node (4 nodes/wave, 16 nodes/block); 8x unrolled
// into 8 independent accumulators for 8 outstanding gathers per slot.
__global__ __launch_bounds__(256) void k_agg(const float* __restrict__ Gin,
                                             const int* __restrict__ col,
                                             const int* __restrict__ row_ptr,
                                             const float* __restrict__ dinv,
                                             const float* __restrict__ bias,
                                             float* __restrict__ Xout, int relu) {
  const float2* G2 = reinterpret_cast<const float2*>(Gin);
  int t = threadIdx.x;
  int h = t & 15;          // float2 index within row (feats 2h, 2h+1)
  int slot = t >> 4;       // 0..15 node slot within block
  int n = blockIdx.x * 16 + slot;
  int beg = row_ptr[n], end = row_ptr[n + 1];

  float2 a0 = G2[(size_t)n * 16 + h];  // self-loop term
  float2 a1 = {0.f, 0.f}, a2 = {0.f, 0.f}, a3 = {0.f, 0.f};
  float2 a4 = {0.f, 0.f}, a5 = {0.f, 0.f}, a6 = {0.f, 0.f}, a7 = {0.f, 0.f};

  int i = beg;
  for (; i + 8 <= end; i += 8) {
    int s0 = __builtin_nontemporal_load(&col[i + 0]);
    int s1 = __builtin_nontemporal_load(&col[i + 1]);
    int s2 = __builtin_nontemporal_load(&col[i + 2]);
    int s3 = __builtin_nontemporal_load(&col[i + 3]);
    int s4 = __builtin_nontemporal_load(&col[i + 4]);
    int s5 = __builtin_nontemporal_load(&col[i + 5]);
    int s6 = __builtin_nontemporal_load(&col[i + 6]);
    int s7 = __builtin_nontemporal_load(&col[i + 7]);
    float2 g0 = G2[(size_t)s0 * 16 + h];
    float2 g1 = G2[(size_t)s1 * 16 + h];
    float2 g2 = G2[(size_t)s2 * 16 + h];
    float2 g3 = G2[(size_t)s3 * 16 + h];
    float2 g4 = G2[(size_t)s4 * 16 + h];
    float2 g5 = G2[(size_t)s5 * 16 + h];
    float2 g6 = G2[(size_t)s6 * 16 + h];
    float2 g7 = G2[(size_t)s7 * 16 + h];
    a0.x += g0.x; a0.y += g0.y;
    a1.x += g1.x; a1.y += g1.y;
    a2.x += g2.x; a2.y += g2.y;
    a3.x += g3.x; a3.y += g3.y;
    a4.x += g4.x; a4.y += g4.y;
    a5.x += g5.x; a5.y += g5.y;
    a6.x += g6.x; a6.y += g6.y;
    a7.x += g7.x; a7.y += g7.y;
  }
  for (; i < end; i++) {
    int s = __builtin_nontemporal_load(&col[i]);
    float2 g = G2[(size_t)s * 16 + h];
    a0.x += g.x; a0.y += g.y;
  }
  a0.x += a1.x + a2.x + a3.x + a4.x + a5.x + a6.x + a7.x;
  a0.y += a1.y + a2.y + a3.y + a4.y + a5.y + a6.y + a7.y;

  float s = dinv[n];
  float2 b = reinterpret_cast<const float2*>(bias)[h];
  float2 v;
  v.x = s * a0.x + b.x;
  v.y = s * a0.y + b.y;
  if (relu) {
    v.x = fmaxf(v.x, 0.f);
    v.y = fmaxf(v.y, 0.f);
  }
  reinterpret_cast<float2*>(Xout)[(size_t)n * 16 + h] = v;
}

// Mean-pool: batch is sorted, so flush-on-graph-change keeps atomics rare.
__global__ __launch_bounds__(256) void k_pool(const float* __restrict__ X,
                                              const int* __restrict__ batch,
                                              float* __restrict__ sums,
                                              int* __restrict__ counts) {
  int t = threadIdx.x;
  int f = t & 31, slot = t >> 5;
  int base = blockIdx.x * 512;
  float acc = 0.f;
  int cnt = 0, cur = -1;
  for (int i = 0; i < 64; i++) {
    int n = base + slot + i * 8;
    if (n >= NN) break;
    int g = batch[n];
    if (g != cur) {
      if (cur >= 0) {
        atomicAdd(&sums[cur * HID + f], acc);
        if (f == 0) atomicAdd(&counts[cur], cnt);
      }
      cur = g;
      acc = 0.f;
      cnt = 0;
    }
    acc += X[(size_t)n * HID + f];
    cnt++;
  }
  if (cur >= 0) {
    atomicAdd(&sums[cur * HID + f], acc);
    if (f == 0) atomicAdd(&counts[cur], cnt);
  }
}

__global__ void k_fc(const float* __restrict__ sums, const int* __restrict__ counts,
                     const float* __restrict__ Wfc, const float* __restrict__ bfc,
                     float* __restrict__ out) {
  int idx = blockIdx.x * 256 + threadIdx.x;
  if (idx >= NGR * NC) return;
  int g = idx / NC, c = idx % NC;
  float inv = 1.f / fmaxf((float)counts[g], 1.f);
  float acc = bfc[c];
#pragma unroll
  for (int k = 0; k < HID; k++) acc += sums[g * HID + k] * inv * Wfc[k * NC + c];
  out[idx] = acc;
}

extern "C" void kernel_launch(void* const* d_in, const int* in_sizes, int n_in,
                              void* d_out, int out_size, void* d_ws, size_t ws_size,
                              hipStream_t stream) {
  (void)in_sizes; (void)n_in; (void)out_size; (void)ws_size;
  const float* x = (const float*)d_in[0];
  const int* ei = (const int*)d_in[1];
  const int* batch = (const int*)d_in[2];
  const float* W1 = (const float*)d_in[3];
  const float* b1 = (const float*)d_in[4];
  const float* W2 = (const float*)d_in[5];
  const float* b2 = (const float*)d_in[6];
  const float* W3 = (const float*)d_in[7];
  const float* b3 = (const float*)d_in[8];
  const float* Wfc = (const float*)d_in[9];
  const float* bfc = (const float*)d_in[10];
  float* out = (float*)d_out;

  char* ws = (char*)d_ws;
  size_t off = 0;
  auto alloc = [&](size_t bytes) -> void* {
    void* p = ws + off;
    off = (off + bytes + 255) & ~(size_t)255;
    return p;
  };
  float* dinv = (float*)alloc((size_t)NN * 4);
  int* deg = (int*)alloc((size_t)NN * 4);
  int* row_ptr = (int*)alloc((size_t)(NN + 1) * 4);
  int* cursor = (int*)alloc((size_t)NN * 4);
  int* bsums = (int*)alloc(256 * 4);
  int* bcur = (int*)alloc(NBUK * 4);
  int* col = (int*)alloc((size_t)EE * 4);
  // Union region: bpair (PassA/B only) overlaps Gbuf+Abuf (GEMM phase only).
  size_t bpair_bytes = (size_t)NBUK * BSLACK * 8;       // 26.4 MB
  size_t gbuf_bytes = (size_t)NN * HID * 4;             // 12.8 MB
  char* uni = (char*)alloc(bpair_bytes > 2 * gbuf_bytes ? bpair_bytes : 2 * gbuf_bytes);
  int2* bpair = (int2*)uni;
  float* Gbuf = (float*)uni;
  float* Abuf = (float*)(uni + gbuf_bytes);
  float* sums = (float*)alloc((size_t)NGR * HID * 4);
  int* counts = (int*)alloc((size_t)NGR * 4);

  hipMemsetAsync(deg, 0, (size_t)NN * 4, stream);
  hipMemsetAsync(sums, 0, (size_t)NGR * HID * 4, stream);
  hipMemsetAsync(counts, 0, (size_t)NGR * 4, stream);

  k_init<<<1, NBUK, 0, stream>>>(bcur);
  k_bucket<<<EE / 6250, 256, 0, stream>>>(ei, deg, bcur, bpair);  // 512 blocks
  k_dinv<<<(NN + 255) / 256, 256, 0, stream>>>(deg, dinv);
  int nb = (NN + 1023) / 1024;  // 98
  k_scanA<<<nb, 256, 0, stream>>>(deg, row_ptr, bsums);
  k_scanB<<<1, 256, 0, stream>>>(bsums, nb);
  k_scanC<<<nb, 256, 0, stream>>>(row_ptr, cursor, bsums);
  k_scatter_b<<<NBUK * SUBB, 256, 0, stream>>>(bpair, bcur, cursor, col);

  k_gemm<FIN><<<(NN + 127) / 128, 256, 0, stream>>>(x, W1, dinv, Gbuf);
  k_agg<<<NN / 16, 256, 0, stream>>>(Gbuf, col, row_ptr, dinv, b1, Abuf, 1);
  k_gemm<HID><<<(NN + 127) / 128, 256, 0, stream>>>(Abuf, W2, dinv, Gbuf);
  k_agg<<<NN / 16, 256, 0, stream>>>(Gbuf, col, row_ptr, dinv, b2, Abuf, 1);
  k_gemm<HID><<<(NN + 127) / 128, 256, 0, stream>>>(Abuf, W3, dinv, Gbuf);
  k_agg<<<NN / 16, 256, 0, stream>>>(Gbuf, col, row_ptr, dinv, b3, Abuf, 0);

  k_pool<<<(NN + 511) / 512, 256, 0, stream>>>(Abuf, batch, sums, counts);
  k_fc<<<(NGR * NC + 255) / 256, 256, 0, stream>>>(sums, counts, Wfc, bfc, out);
}